// Round 5
// baseline (487.802 us; speedup 1.0000x reference)
//
#include <hip/hip_runtime.h>
#include <hip/hip_bf16.h>
#include <stdint.h>

// ---------------- problem constants ----------------
#define N_NODES   20000
#define N_EDGES   320000
#define E_TOT     (N_EDGES + N_NODES)   // 340000 incl. self-loops
#define IN_CH     256
#define HID       128
#define HEADS     4
#define OUT_CH    200
#define NUM_GRAPHS 64
#define M_PAD     20096                 // 157 * 128

typedef __bf16 bf16_t;
typedef __bf16 bf16x8 __attribute__((ext_vector_type(8)));
typedef __bf16 bf16x2 __attribute__((ext_vector_type(2)));
typedef float  f32x4  __attribute__((ext_vector_type(4)));

// ---------------- inline dtype detection (per-wave, ~200 cycles) ----------------
__device__ __forceinline__ bool detect_bf16(const unsigned short* __restrict__ xu16) {
  int lane = threadIdx.x & 63;
  unsigned short v = xu16[2 * lane];
  int e = (v >> 7) & 0xff;
  unsigned long long b = __ballot(e >= 90 && e <= 160);
  return __popcll(b) >= 40;
}
__device__ __forceinline__ bool detect_i64(const unsigned* __restrict__ eidx) {
  int lane = threadIdx.x & 63;
  unsigned long long b = __ballot(eidx[2 * lane + 1] == 0u);
  return __popcll(b) >= 32;
}

// ---------------- prep: weights cvt/transpose + small arrays + int cvt + deg hist ----
struct SmallCvt {
  const void* src[11];
  bf16_t* dst[11];
  int n[11];
};

__global__ void prep(const void* __restrict__ W1, const void* __restrict__ W2,
                     const void* __restrict__ W3, bf16_t* __restrict__ W1T,
                     bf16_t* __restrict__ W2T, bf16_t* __restrict__ W3T,
                     SmallCvt tab, const unsigned short* __restrict__ xu16,
                     const int* __restrict__ eidx, const int* __restrict__ batch,
                     int* __restrict__ esrc, int* __restrict__ edst,
                     int* __restrict__ b32, int* __restrict__ deg) {
  bool isbf = detect_bf16(xu16);
  bool i64  = detect_i64((const unsigned*)eidx);
  int i = blockIdx.x * 256 + threadIdx.x;
  if (i < N_EDGES) {
    int s = i64 ? eidx[2 * i] : eidx[i];
    int d = i64 ? eidx[2 * (N_EDGES + i)] : eidx[N_EDGES + i];
    esrc[i] = s;
    edst[i] = d;
    atomicAdd(&deg[d], 1);          // random bins; round-4 lesson: never few sorted bins
  }
  if (i < N_NODES) {
    b32[i] = i64 ? batch[2 * i] : batch[i];
    atomicAdd(&deg[i], 1);          // self-loop
  }
  if (i < 131072) {                 // W1 [256,512] -> W1T [512,256]
    int k = i >> 9, nn = i & 511;
    bf16_t v = isbf ? ((const bf16_t*)W1)[i] : (bf16_t)((const float*)W1)[i];
    W1T[(size_t)nn * 256 + k] = v;
  } else if (i < 131072 + 262144) { // W2 [512,512]
    int i2 = i - 131072;
    int k = i2 >> 9, nn = i2 & 511;
    bf16_t v = isbf ? ((const bf16_t*)W2)[i2] : (bf16_t)((const float*)W2)[i2];
    W2T[(size_t)nn * 512 + k] = v;
  } else if (i < 131072 + 262144 + 65536) {  // W3 [512,128]
    int i3 = i - 131072 - 262144;
    int k = i3 >> 7, nn = i3 & 127;
    bf16_t v = isbf ? ((const bf16_t*)W3)[i3] : (bf16_t)((const float*)W3)[i3];
    W3T[(size_t)nn * 512 + k] = v;
  } else {
    int j = i - 458752;
    for (int s = 0; s < 11; ++s) {
      if (j < tab.n[s]) {
        tab.dst[s][j] = isbf ? ((const bf16_t*)tab.src[s])[j]
                             : (bf16_t)((const float*)tab.src[s])[j];
        break;
      }
      j -= tab.n[s];
    }
  }
}

// ---------------- CSR offsets: single-block scan, per-thread register tiles ----------
__launch_bounds__(1024)
__global__ void scan_deg_block(const int* __restrict__ deg, int* __restrict__ off,
                               int* __restrict__ cursor) {
  const int PT = 20;                   // 1024*20 = 20480 >= N_NODES
  int t = threadIdx.x;
  int lane = t & 63, wid = t >> 6;     // 16 waves
  int base = t * PT;
  int v[PT];
  int s = 0;
#pragma unroll
  for (int j = 0; j < PT; ++j) {
    int i = base + j;
    v[j] = (i < N_NODES) ? deg[i] : 0;
    s += v[j];
  }
  int x = s;
  for (int d = 1; d < 64; d <<= 1) {
    int y = __shfl_up(x, d);
    if (lane >= d) x += y;
  }
  __shared__ int wsum[16];
  if (lane == 63) wsum[wid] = x;
  __syncthreads();
  if (t < 16) {
    int y = wsum[t];
    for (int d = 1; d < 16; d <<= 1) {
      int z = __shfl_up(y, d);
      if (t >= d) y += z;
    }
    wsum[t] = y;
  }
  __syncthreads();
  int run = (wid > 0 ? wsum[wid - 1] : 0) + (x - s);
#pragma unroll
  for (int j = 0; j < PT; ++j) {
    int i = base + j;
    if (i < N_NODES) { off[i] = run; cursor[i] = 0; run += v[j]; }
  }
  if (t == 1023) off[N_NODES] = run;
}

__global__ void scatter_kernel(const int* __restrict__ esrc, const int* __restrict__ edst,
                               const int* __restrict__ off, int* __restrict__ cursor,
                               int* __restrict__ csr_src) {
  int e = blockIdx.x * 256 + threadIdx.x;
  if (e >= E_TOT) return;
  int s, d;
  if (e < N_EDGES) { s = esrc[e]; d = edst[e]; } else { s = d = e - N_EDGES; }
  int pos = off[d] + atomicAdd(&cursor[d], 1);
  csr_src[pos] = s;
}

// ---------------- MFMA GEMM + fused alpha epilogue, XCD-grouped grid ----------------
// Round-12 dbuf k-pipeline kept (neutral, not harmful).  NBN = N/128.
template<bool MAYBE_F32, int NBN>
__launch_bounds__(256)
__global__ void gemm_bf16(const void* __restrict__ Av, const bf16_t* __restrict__ BT,
                          bf16_t* __restrict__ C, int M, int N, int K,
                          const bf16_t* __restrict__ a_src, const bf16_t* __restrict__ a_dst,
                          float* __restrict__ as, float* __restrict__ ad, int H) {
  bool isbf = MAYBE_F32 ? detect_bf16((const unsigned short*)Av) : true;
  const bf16_t* A  = (const bf16_t*)Av;
  const float*  Af = (const float*)Av;
  __shared__ bf16_t As[2][128 * 32];
  __shared__ bf16_t Bs[2][128 * 32];
  __shared__ float sred[2][128];
  __shared__ float dred[2][128];
  const int tid  = threadIdx.x;
  const int lane = tid & 63;
  const int w    = tid >> 6;
  const int wm   = w & 1, wn = w >> 1;
  // XCD-grouped decode: id%8 == bm%8
  const int id   = blockIdx.x;
  const int bmq  = id / (8 * NBN);
  const int rem  = id % (8 * NBN);
  const int bm   = (bmq * 8 + (rem & 7)) * 128;
  const int bn   = (rem >> 3) * 128;
  const int quad = lane >> 4;
  const int l16  = lane & 15;
  const int hd   = bn >> 7;            // head owned by this block column

  f32x4 zero = {0.f, 0.f, 0.f, 0.f};
  f32x4 acc[4][4];
  for (int i = 0; i < 4; ++i)
    for (int j = 0; j < 4; ++j) acc[i][j] = zero;

  const int c0 = tid, c1 = tid + 256;         // 16B chunks of the 128x32 tile
  const int r0 = c0 >> 2, s0 = c0 & 3;
  const int r1 = c1 >> 2, s1 = c1 & 3;
  int ga0 = bm + r0; if (ga0 > M - 1) ga0 = M - 1;   // clamp: garbage rows never stored
  int ga1 = bm + r1; if (ga1 > M - 1) ga1 = M - 1;

  // issue the 4 async global->LDS loads for k-tile k0 into buffer b
  auto stage = [&](int b, int k0) {
    __builtin_amdgcn_global_load_lds(
        (const __attribute__((address_space(1))) void*)(A + (size_t)ga0 * K + k0 + s0 * 8),
        (__attribute__((address_space(3))) void*)(&As[b][(size_t)(w * 64) * 8]), 16, 0, 0);
    __builtin_amdgcn_global_load_lds(
        (const __attribute__((address_space(1))) void*)(BT + (size_t)(bn + r0) * K + k0 + s0 * 8),
        (__attribute__((address_space(3))) void*)(&Bs[b][(size_t)(w * 64) * 8]), 16, 0, 0);
    __builtin_amdgcn_global_load_lds(
        (const __attribute__((address_space(1))) void*)(A + (size_t)ga1 * K + k0 + s1 * 8),
        (__attribute__((address_space(3))) void*)(&As[b][(size_t)(256 + w * 64) * 8]), 16, 0, 0);
    __builtin_amdgcn_global_load_lds(
        (const __attribute__((address_space(1))) void*)(BT + (size_t)(bn + r1) * K + k0 + s1 * 8),
        (__attribute__((address_space(3))) void*)(&Bs[b][(size_t)(256 + w * 64) * 8]), 16, 0, 0);
  };

  auto mma_step = [&](int b) {
    bf16x8 af[4], bfr[4];
    for (int mt = 0; mt < 4; ++mt) {
      int m_local = wm * 64 + mt * 16 + l16;
      af[mt] = *(const bf16x8*)(&As[b][m_local * 32 + quad * 8]);
    }
    for (int nt = 0; nt < 4; ++nt) {
      int n_local = wn * 64 + nt * 16 + l16;
      bfr[nt] = *(const bf16x8*)(&Bs[b][n_local * 32 + quad * 8]);
    }
    for (int mt = 0; mt < 4; ++mt)
      for (int nt = 0; nt < 4; ++nt)
        acc[mt][nt] = __builtin_amdgcn_mfma_f32_16x16x32_bf16(af[mt], bfr[nt], acc[mt][nt], 0, 0, 0);
  };

  if (!MAYBE_F32 || isbf) {
    // ---- bf16 path: dbuf pipeline.  Tile t+1 loads fly across tile t's compute.
    stage(0, 0);
    __syncthreads();                    // tile 0 landed
    const int NT = K >> 5;
    for (int t = 0; t < NT; ++t) {
      int cur = t & 1;
      if (t + 1 < NT) stage(cur ^ 1, (t + 1) << 5);
      mma_step(cur);
      __syncthreads();                  // drains t+1 loads; all reads of buf[cur] done
    }
  } else {
    // ---- f32 input path (layer 1 when x is f32): original reg-staged single-buffer
    for (int k0 = 0; k0 < K; k0 += 32) {
      bf16x8 va0, va1;
      const float* p0 = Af + (size_t)ga0 * K + k0 + s0 * 8;
      const float* p1 = Af + (size_t)ga1 * K + k0 + s1 * 8;
      f32x4 l0 = *(const f32x4*)p0, h0 = *(const f32x4*)(p0 + 4);
      f32x4 l1 = *(const f32x4*)p1, h1 = *(const f32x4*)(p1 + 4);
      for (int j = 0; j < 4; ++j) {
        va0[j] = (bf16_t)l0[j]; va0[j + 4] = (bf16_t)h0[j];
        va1[j] = (bf16_t)l1[j]; va1[j + 4] = (bf16_t)h1[j];
      }
      bf16x8 vb0 = *(const bf16x8*)(BT + (size_t)(bn + r0) * K + k0 + s0 * 8);
      bf16x8 vb1 = *(const bf16x8*)(BT + (size_t)(bn + r1) * K + k0 + s1 * 8);
      __syncthreads();
      *(bf16x8*)(&As[0][c0 * 8]) = va0;
      *(bf16x8*)(&Bs[0][c0 * 8]) = vb0;
      *(bf16x8*)(&As[0][c1 * 8]) = va1;
      *(bf16x8*)(&Bs[0][c1 * 8]) = vb1;
      __syncthreads();
      mma_step(0);
    }
  }

  // ---- C store.  C/D layout: col=lane&15, row=(lane>>4)*4+r   [m89-verified]
  for (int mt = 0; mt < 4; ++mt) {
    for (int r = 0; r < 4; ++r) {
      int m = bm + wm * 64 + mt * 16 + quad * 4 + r;
      if (m >= M) continue;
      for (int nt = 0; nt < 4; ++nt) {
        int n = bn + wn * 64 + nt * 16 + l16;
        C[(size_t)m * N + n] = (bf16_t)acc[mt][nt][r];
      }
    }
  }

  // ---- fused alpha epilogue: per-row dots over this block's 128 columns
  float av[4], dv[4];
  for (int nt = 0; nt < 4; ++nt) {
    int ch = wn * 64 + nt * 16 + l16;            // channel within head
    av[nt] = (float)a_src[hd * 128 + ch];
    dv[nt] = (float)a_dst[hd * 128 + ch];
  }
  for (int mt = 0; mt < 4; ++mt) {
    for (int r = 0; r < 4; ++r) {
      float s = acc[mt][0][r] * av[0] + acc[mt][1][r] * av[1]
              + acc[mt][2][r] * av[2] + acc[mt][3][r] * av[3];
      float d = acc[mt][0][r] * dv[0] + acc[mt][1][r] * dv[1]
              + acc[mt][2][r] * dv[2] + acc[mt][3][r] * dv[3];
      for (int o = 1; o < 16; o <<= 1) {
        s += __shfl_xor(s, o);
        d += __shfl_xor(d, o);
      }
      if (l16 == 0) {
        int row_local = wm * 64 + mt * 16 + quad * 4 + r;
        sred[wn][row_local] = s;
        dred[wn][row_local] = d;
      }
    }
  }
  __syncthreads();
  if (tid < 128) {
    int m = bm + tid;
    if (m < M) {
      as[m * H + hd] = sred[0][tid] + sred[1][tid];
      ad[m * H + hd] = dred[0][tid] + dred[1][tid];
    }
  }
}

// ---------------- edge weights + per-node denominators, 2 heads per pass -------------
// One wave per node; lane = (edge_in_group<<1) | (head-h0).  Computes w=exp(lrelu(e))
// ONCE per edge per head (kills round-10's 8x redo), NT-stores to head-planar wbuf.
__launch_bounds__(256)
__global__ void edge_w(const int* __restrict__ off, const int* __restrict__ csr_src,
                       const float* __restrict__ as, const float* __restrict__ ad,
                       float* __restrict__ wbuf, float* __restrict__ den, int h0) {
  int lane = threadIdx.x & 63;
  int n = blockIdx.x * 4 + (threadIdx.x >> 6);
  if (n >= N_NODES) return;
  int start = __builtin_amdgcn_readfirstlane(off[n]);
  int end   = __builtin_amdgcn_readfirstlane(off[n + 1]);
  int ei = lane >> 1, hh = h0 + (lane & 1);
  float adv = ad[n * 4 + hh];
  float psum = 0.f;
  for (int p0 = start; p0 < end; p0 += 32) {
    int p = p0 + ei;
    bool valid = p < end;
    int src = csr_src[valid ? p : end - 1];
    float e = as[src * 4 + hh] + adv;
    e = e > 0.f ? e : 0.2f * e;
    float wv = __expf(e);
    if (valid) {
      __builtin_nontemporal_store(wv, &wbuf[(size_t)(lane & 1) * E_TOT + p]);
      psum += wv;
    }
  }
  for (int o = 2; o < 64; o <<= 1) psum += __shfl_xor(psum, o);  // reduce same-head lanes
  if (lane < 2) den[n * 4 + h0 + lane] = psum;
}

// ---------------- L2-resident sliced aggregation (layers 1-2, 256 ch per pass) -------
// xcd = bid&7 (round-10-verified %8->XCD mapping).  slice = xcd>>1: 4 slices x 64ch,
// TWO XCDs per slice splitting the nodes, so all 8 XCDs are busy and each caches only
// its 64-ch slice: 20000*128B = 2.56MB < 4MB XCD L2 -> gathers become L2 hits, lifting
// the MSHR-latency-limited gather bandwidth.  Each per-edge wave gather is exactly one
// aligned 128B line.  Weights/denoms precomputed (edge_w); out NT-stored.
__launch_bounds__(256)
__global__ void agg_sliced(const bf16_t* __restrict__ h, const int* __restrict__ off,
                           const int* __restrict__ csr_src, const float* __restrict__ wbuf,
                           const float* __restrict__ den, const bf16_t* __restrict__ bias,
                           bf16_t* __restrict__ outp, int ch0) {
  int lane  = threadIdx.x & 63;
  int bid   = blockIdx.x;
  int xcd   = bid & 7;
  int slice = xcd >> 1;
  int grp   = (bid >> 3) * 2 + (xcd & 1);
  int n     = grp * 4 + (threadIdx.x >> 6);
  if (n >= N_NODES) return;
  int ch = ch0 + slice * 64 + lane;    // channel in [ch0, ch0+256)
  int hd = ch >> 7;                    // head
  int start = __builtin_amdgcn_readfirstlane(off[n]);
  int end   = __builtin_amdgcn_readfirstlane(off[n + 1]);
  const float* wp = wbuf + (size_t)(hd & 1) * E_TOT;
  float acc = 0.f;
  int pos = start;
  for (; pos + 3 < end; pos += 4) {
    int s0 = __builtin_amdgcn_readfirstlane(csr_src[pos]);
    int s1 = __builtin_amdgcn_readfirstlane(csr_src[pos + 1]);
    int s2 = __builtin_amdgcn_readfirstlane(csr_src[pos + 2]);
    int s3 = __builtin_amdgcn_readfirstlane(csr_src[pos + 3]);
    float w0 = __builtin_nontemporal_load(&wp[pos]);
    float w1 = __builtin_nontemporal_load(&wp[pos + 1]);
    float w2 = __builtin_nontemporal_load(&wp[pos + 2]);
    float w3 = __builtin_nontemporal_load(&wp[pos + 3]);
    float v0 = (float)h[(size_t)s0 * 512 + ch];
    float v1 = (float)h[(size_t)s1 * 512 + ch];
    float v2 = (float)h[(size_t)s2 * 512 + ch];
    float v3 = (float)h[(size_t)s3 * 512 + ch];
    acc += (w0 * v0 + w1 * v1) + (w2 * v2 + w3 * v3);
  }
  for (; pos < end; ++pos) {
    int s0 = __builtin_amdgcn_readfirstlane(csr_src[pos]);
    float w0 = __builtin_nontemporal_load(&wp[pos]);
    acc += w0 * (float)h[(size_t)s0 * 512 + ch];
  }
  float dn = den[n * 4 + hd];
  float o = acc / (dn + 1e-16f) + (float)bias[ch];
  o = o > 0.f ? o : expm1f(o);         // elu
  __builtin_nontemporal_store((bf16_t)o, &outp[(size_t)n * 512 + ch]);
}

// ---------------- fused softmax + aggregation + bias + ELU (layer 3) -----------------
template<int CPL>
__launch_bounds__(256)
__global__ void agg_fused(const bf16_t* __restrict__ h, const int* __restrict__ off,
                          const int* __restrict__ csr_src, const float* __restrict__ as,
                          const float* __restrict__ ad, const bf16_t* __restrict__ bias,
                          bf16_t* __restrict__ outp, int H) {
  typedef __bf16 vec_t __attribute__((ext_vector_type(CPL)));
  const int C = CPL * 64;
  int lane = threadIdx.x & 63;
  int n = blockIdx.x * 4 + (threadIdx.x >> 6);
  if (n >= N_NODES) return;
  int start = __builtin_amdgcn_readfirstlane(off[n]);
  int end   = __builtin_amdgcn_readfirstlane(off[n + 1]);
  int c0 = lane * CPL;
  int hd = c0 >> 7;
  float adv = ad[n * H + hd];
  float acc[CPL];
  for (int j = 0; j < CPL; ++j) acc[j] = 0.f;
  float den = 0.f;

  int pos = start;
  for (; pos + 3 < end; pos += 4) {
    int s0 = __builtin_amdgcn_readfirstlane(csr_src[pos]);
    int s1 = __builtin_amdgcn_readfirstlane(csr_src[pos + 1]);
    int s2 = __builtin_amdgcn_readfirstlane(csr_src[pos + 2]);
    int s3 = __builtin_amdgcn_readfirstlane(csr_src[pos + 3]);
    vec_t hv0 = *(const vec_t*)(h + (size_t)s0 * C + c0);
    vec_t hv1 = *(const vec_t*)(h + (size_t)s1 * C + c0);
    vec_t hv2 = *(const vec_t*)(h + (size_t)s2 * C + c0);
    vec_t hv3 = *(const vec_t*)(h + (size_t)s3 * C + c0);
    float e0 = as[s0 * H + hd] + adv; e0 = e0 > 0.f ? e0 : 0.2f * e0;
    float e1 = as[s1 * H + hd] + adv; e1 = e1 > 0.f ? e1 : 0.2f * e1;
    float e2 = as[s2 * H + hd] + adv; e2 = e2 > 0.f ? e2 : 0.2f * e2;
    float e3 = as[s3 * H + hd] + adv; e3 = e3 > 0.f ? e3 : 0.2f * e3;
    float w0 = __expf(e0), w1 = __expf(e1), w2 = __expf(e2), w3 = __expf(e3);
    den += (w0 + w1) + (w2 + w3);
    for (int j = 0; j < CPL; ++j)
      acc[j] += (w0 * (float)hv0[j] + w1 * (float)hv1[j])
              + (w2 * (float)hv2[j] + w3 * (float)hv3[j]);
  }
  for (; pos < end; ++pos) {
    int s0 = __builtin_amdgcn_readfirstlane(csr_src[pos]);
    vec_t hv0 = *(const vec_t*)(h + (size_t)s0 * C + c0);
    float e0 = as[s0 * H + hd] + adv; e0 = e0 > 0.f ? e0 : 0.2f * e0;
    float w0 = __expf(e0);
    den += w0;
    for (int j = 0; j < CPL; ++j) acc[j] += w0 * (float)hv0[j];
  }

  float inv = 1.f / (den + 1e-16f);
  vec_t ov;
  for (int j = 0; j < CPL; ++j) {
    float o = acc[j] * inv + (float)bias[c0 + j];
    o = o > 0.f ? o : expm1f(o);         // elu
    ov[j] = (bf16_t)o;
  }
  *(vec_t*)(outp + (size_t)n * C + c0) = ov;
}

// ---------------- merged mean-pool + FC: one block per graph, no atomics -------------
__launch_bounds__(256)
__global__ void pool_fc2(const bf16_t* __restrict__ h3, const int* __restrict__ batch,
                         const bf16_t* __restrict__ fcw, const bf16_t* __restrict__ fcb,
                         void* __restrict__ outp, const unsigned short* __restrict__ xu16) {
  bool isbf = detect_bf16(xu16);
  int g = blockIdx.x;
  int lo = 0, hi = N_NODES;
  while (lo < hi) { int mid = (lo + hi) >> 1; if (batch[mid] < g) lo = mid + 1; else hi = mid; }
  int start = lo;
  hi = N_NODES;
  while (lo < hi) { int mid = (lo + hi) >> 1; if (batch[mid] < g + 1) lo = mid + 1; else hi = mid; }
  int end = lo, cnt = end - start;

  int t = threadIdx.x;
  int wave = t >> 6, lane = t & 63;
  int c0 = lane * 2;
  float a0 = 0.f, a1 = 0.f;
  for (int n = start + wave; n < end; n += 4) {
    bf16x2 v = *(const bf16x2*)(h3 + (size_t)n * HID + c0);
    a0 += (float)v[0];
    a1 += (float)v[1];
  }
  __shared__ float red[4][HID];
  red[wave][c0] = a0;
  red[wave][c0 + 1] = a1;
  __syncthreads();
  __shared__ float pooled[HID];
  if (t < HID) {
    float s = red[0][t] + red[1][t] + red[2][t] + red[3][t];
    pooled[t] = s / (float)(cnt > 0 ? cnt : 1);
  }
  __syncthreads();
  if (t < OUT_CH) {
    float a = (float)fcb[t];
    for (int c = 0; c < HID; ++c) a += pooled[c] * (float)fcw[c * OUT_CH + t];
    if (isbf) ((bf16_t*)outp)[g * OUT_CH + t] = (bf16_t)a;
    else      ((float*)outp)[g * OUT_CH + t] = a;
  }
}

// ---------------- launcher ----------------
extern "C" void kernel_launch(void* const* d_in, const int* in_sizes, int n_in,
                              void* d_out, int out_size, void* d_ws, size_t ws_size,
                              hipStream_t stream) {
  const void* x    = d_in[0];
  const void* eidx = d_in[1];
  const void* batch= d_in[2];
  const void* W1   = d_in[3];
  const void* a_s1 = d_in[4];
  const void* a_d1 = d_in[5];
  const void* b1   = d_in[6];
  const void* W2   = d_in[7];
  const void* a_s2 = d_in[8];
  const void* a_d2 = d_in[9];
  const void* b2   = d_in[10];
  const void* W3   = d_in[11];
  const void* a_s3 = d_in[12];
  const void* a_d3 = d_in[13];
  const void* b3   = d_in[14];
  const void* fcw  = d_in[15];
  const void* fcb  = d_in[16];
  const unsigned short* xu16 = (const unsigned short*)x;

  // Workspace budget lesson (round 14): previous working layout = 47.02 MB; adding a
  // standalone 5.8MB wbuf crashed the container (ws overrun).  wbuf (2.72MB, two head
  // planes) now OVERLAYS the prep-only buffers deg/cursor/esrc32/edst32 (2.72MB dead
  // after scatter_kernel).  Total = 47.34 MB.
  char* p = (char*)d_ws;
  auto carve = [&](size_t nbytes) { char* r = p; p += (nbytes + 255) & ~(size_t)255; return r; };
  bf16_t*   W1T    = (bf16_t*)carve((size_t)512 * 256 * 2);
  bf16_t*   W2T    = (bf16_t*)carve((size_t)512 * 512 * 2);
  bf16_t*   W3T    = (bf16_t*)carve((size_t)128 * 512 * 2);
  bf16_t*   hA     = (bf16_t*)carve((size_t)M_PAD * 512 * 2);
  bf16_t*   hB     = (bf16_t*)carve((size_t)M_PAD * 512 * 2);
  bf16_t*   sm     = (bf16_t*)carve((size_t)32768 * 2);
  bf16_t *as1b = sm, *ad1b = sm + 512, *b1b = sm + 1024,
         *as2b = sm + 1536, *ad2b = sm + 2048, *b2b = sm + 2560,
         *as3b = sm + 3072, *ad3b = sm + 3200, *b3b = sm + 3328,
         *fcwb = sm + 3456, *fcbb = sm + 29056;
  float*    asb    = (float*)carve((size_t)N_NODES * 4 * 4);
  float*    adb    = (float*)carve((size_t)N_NODES * 4 * 4);
  float*    denb   = (float*)carve((size_t)N_NODES * 4 * 4);
  int*      off    = (int*)carve((size_t)(N_NODES + 1) * 4);
  int*      csr_src= (int*)carve((size_t)E_TOT * 4);
  int*      bat32  = (int*)carve((size_t)N_NODES * 4);
  // overlay region: prep-time {deg, cursor, esrc32, edst32} == agg-time {wbuf}
  char*     ov     = carve(2720256);
  int*      deg    = (int*)ov;
  int*      cursor = (int*)(ov + 80128);
  int*      esrc32 = (int*)(ov + 160256);
  int*      edst32 = (int*)(ov + 1440256);
  float*    wbuf   = (float*)ov;      // 2 * E_TOT * 4 = 2,720,000 <= 2,720,256

  dim3 b256(256);
  const int NG4 = (N_NODES + 3) / 4;   // wave-per-node grids

  SmallCvt tab;
  const void* srcs[11] = {a_s1, a_d1, b1, a_s2, a_d2, b2, a_s3, a_d3, b3, fcw, fcb};
  bf16_t* dsts[11] = {as1b, ad1b, b1b, as2b, ad2b, b2b, as3b, ad3b, b3b, fcwb, fcbb};
  int ns[11] = {512, 512, 512, 512, 512, 512, 128, 128, 128, 25600, 200};
  for (int i = 0; i < 11; ++i) { tab.src[i] = srcs[i]; tab.dst[i] = dsts[i]; tab.n[i] = ns[i]; }

  hipMemsetAsync(deg, 0, (size_t)N_NODES * 4, stream);
  prep<<<dim3((458752 + 29256 + 255) / 256), b256, 0, stream>>>(
      W1, W2, W3, W1T, W2T, W3T, tab, xu16,
      (const int*)eidx, (const int*)batch, esrc32, edst32, bat32, deg);

  // CSR-by-dst (src-only payload; reused by all 3 layers)
  scan_deg_block<<<dim3(1), dim3(1024), 0, stream>>>(deg, off, cursor);
  scatter_kernel<<<dim3((E_TOT + 255) / 256), b256, 0, stream>>>(esrc32, edst32, off, cursor, csr_src);

  // XCD-grouped 1-D gemm grids: 160 bm slots (157 used) x NBN bn
  const int G4 = 160 * 4, G1 = 160 * 1;
  const int NSL = (NG4 / 2) * 8;       // sliced-agg: 4 slices x 2 XCD-halves, per pass

  // ---- layer 1: x -> hA[.,512] + alpha; 2 half-passes of {edge weights; agg} -> hB
  gemm_bf16<true, 4><<<dim3(G4), b256, 0, stream>>>(x, W1T, hA, N_NODES, 512, 256,
                                                    as1b, ad1b, asb, adb, 4);
  edge_w<<<dim3(NG4), b256, 0, stream>>>(off, csr_src, asb, adb, wbuf, denb, 0);
  agg_sliced<<<dim3(NSL), b256, 0, stream>>>(hA, off, csr_src, wbuf, denb, b1b, hB, 0);
  edge_w<<<dim3(NG4), b256, 0, stream>>>(off, csr_src, asb, adb, wbuf, denb, 2);
  agg_sliced<<<dim3(NSL), b256, 0, stream>>>(hA, off, csr_src, wbuf, denb, b1b, hB, 256);

  // ---- layer 2
  gemm_bf16<false, 4><<<dim3(G4), b256, 0, stream>>>(hB, W2T, hA, N_NODES, 512, 512,
                                                     as2b, ad2b, asb, adb, 4);
  edge_w<<<dim3(NG4), b256, 0, stream>>>(off, csr_src, asb, adb, wbuf, denb, 0);
  agg_sliced<<<dim3(NSL), b256, 0, stream>>>(hA, off, csr_src, wbuf, denb, b2b, hB, 0);
  edge_w<<<dim3(NG4), b256, 0, stream>>>(off, csr_src, asb, adb, wbuf, denb, 2);
  agg_sliced<<<dim3(NSL), b256, 0, stream>>>(hA, off, csr_src, wbuf, denb, b2b, hB, 256);

  // ---- layer 3 (h rows 256B; 5.1MB doesn't fit an XCD L2 -> keep fused form)
  gemm_bf16<false, 1><<<dim3(G1), b256, 0, stream>>>(hB, W3T, hA, N_NODES, 128, 512,
                                                     as3b, ad3b, asb, adb, 1);
  agg_fused<2><<<dim3(NG4), b256, 0, stream>>>(hA, off, csr_src, asb, adb, b3b, hB, 1);

  // ---- merged mean-pool + FC
  pool_fc2<<<dim3(NUM_GRAPHS), b256, 0, stream>>>(hB, bat32, fcwb, fcbb, d_out, xu16);
}

// Round 6
// 360.081 us; speedup vs baseline: 1.3547x; 1.3547x over previous
//
#include <hip/hip_runtime.h>
#include <hip/hip_bf16.h>
#include <stdint.h>

// ---------------- problem constants ----------------
#define N_NODES   20000
#define N_EDGES   320000
#define E_TOT     (N_EDGES + N_NODES)   // 340000 incl. self-loops
#define IN_CH     256
#define HID       128
#define HEADS     4
#define OUT_CH    200
#define NUM_GRAPHS 64
#define M_PAD     20096                 // 157 * 128

typedef __bf16 bf16_t;
typedef __bf16 bf16x8 __attribute__((ext_vector_type(8)));
typedef __bf16 bf16x2 __attribute__((ext_vector_type(2)));
typedef float  f32x4  __attribute__((ext_vector_type(4)));

// ---------------- inline dtype detection (per-wave, ~200 cycles) ----------------
__device__ __forceinline__ bool detect_bf16(const unsigned short* __restrict__ xu16) {
  int lane = threadIdx.x & 63;
  unsigned short v = xu16[2 * lane];
  int e = (v >> 7) & 0xff;
  unsigned long long b = __ballot(e >= 90 && e <= 160);
  return __popcll(b) >= 40;
}
__device__ __forceinline__ bool detect_i64(const unsigned* __restrict__ eidx) {
  int lane = threadIdx.x & 63;
  unsigned long long b = __ballot(eidx[2 * lane + 1] == 0u);
  return __popcll(b) >= 32;
}

// ---------------- prep: weights cvt/transpose + small arrays + int cvt + deg hist ----
struct SmallCvt {
  const void* src[11];
  bf16_t* dst[11];
  int n[11];
};

__global__ void prep(const void* __restrict__ W1, const void* __restrict__ W2,
                     const void* __restrict__ W3, bf16_t* __restrict__ W1T,
                     bf16_t* __restrict__ W2T, bf16_t* __restrict__ W3T,
                     SmallCvt tab, const unsigned short* __restrict__ xu16,
                     const int* __restrict__ eidx, const int* __restrict__ batch,
                     int* __restrict__ esrc, int* __restrict__ edst,
                     int* __restrict__ b32, int* __restrict__ deg) {
  bool isbf = detect_bf16(xu16);
  bool i64  = detect_i64((const unsigned*)eidx);
  int i = blockIdx.x * 256 + threadIdx.x;
  if (i < N_EDGES) {
    int s = i64 ? eidx[2 * i] : eidx[i];
    int d = i64 ? eidx[2 * (N_EDGES + i)] : eidx[N_EDGES + i];
    esrc[i] = s;
    edst[i] = d;
    atomicAdd(&deg[d], 1);          // random bins; round-4 lesson: never few sorted bins
  }
  if (i < N_NODES) {
    b32[i] = i64 ? batch[2 * i] : batch[i];
    atomicAdd(&deg[i], 1);          // self-loop
  }
  if (i < 131072) {                 // W1 [256,512] -> W1T [512,256]
    int k = i >> 9, nn = i & 511;
    bf16_t v = isbf ? ((const bf16_t*)W1)[i] : (bf16_t)((const float*)W1)[i];
    W1T[(size_t)nn * 256 + k] = v;
  } else if (i < 131072 + 262144) { // W2 [512,512]
    int i2 = i - 131072;
    int k = i2 >> 9, nn = i2 & 511;
    bf16_t v = isbf ? ((const bf16_t*)W2)[i2] : (bf16_t)((const float*)W2)[i2];
    W2T[(size_t)nn * 512 + k] = v;
  } else if (i < 131072 + 262144 + 65536) {  // W3 [512,128]
    int i3 = i - 131072 - 262144;
    int k = i3 >> 7, nn = i3 & 127;
    bf16_t v = isbf ? ((const bf16_t*)W3)[i3] : (bf16_t)((const float*)W3)[i3];
    W3T[(size_t)nn * 512 + k] = v;
  } else {
    int j = i - 458752;
    for (int s = 0; s < 11; ++s) {
      if (j < tab.n[s]) {
        tab.dst[s][j] = isbf ? ((const bf16_t*)tab.src[s])[j]
                             : (bf16_t)((const float*)tab.src[s])[j];
        break;
      }
      j -= tab.n[s];
    }
  }
}

// ---------------- CSR offsets: single-block scan, per-thread register tiles ----------
__launch_bounds__(1024)
__global__ void scan_deg_block(const int* __restrict__ deg, int* __restrict__ off,
                               int* __restrict__ cursor) {
  const int PT = 20;                   // 1024*20 = 20480 >= N_NODES
  int t = threadIdx.x;
  int lane = t & 63, wid = t >> 6;     // 16 waves
  int base = t * PT;
  int v[PT];
  int s = 0;
#pragma unroll
  for (int j = 0; j < PT; ++j) {
    int i = base + j;
    v[j] = (i < N_NODES) ? deg[i] : 0;
    s += v[j];
  }
  int x = s;
  for (int d = 1; d < 64; d <<= 1) {
    int y = __shfl_up(x, d);
    if (lane >= d) x += y;
  }
  __shared__ int wsum[16];
  if (lane == 63) wsum[wid] = x;
  __syncthreads();
  if (t < 16) {
    int y = wsum[t];
    for (int d = 1; d < 16; d <<= 1) {
      int z = __shfl_up(y, d);
      if (t >= d) y += z;
    }
    wsum[t] = y;
  }
  __syncthreads();
  int run = (wid > 0 ? wsum[wid - 1] : 0) + (x - s);
#pragma unroll
  for (int j = 0; j < PT; ++j) {
    int i = base + j;
    if (i < N_NODES) { off[i] = run; cursor[i] = 0; run += v[j]; }
  }
  if (t == 1023) off[N_NODES] = run;
}

__global__ void scatter_kernel(const int* __restrict__ esrc, const int* __restrict__ edst,
                               const int* __restrict__ off, int* __restrict__ cursor,
                               int* __restrict__ csr_src) {
  int e = blockIdx.x * 256 + threadIdx.x;
  if (e >= E_TOT) return;
  int s, d;
  if (e < N_EDGES) { s = esrc[e]; d = edst[e]; } else { s = d = e - N_EDGES; }
  int pos = off[d] + atomicAdd(&cursor[d], 1);
  csr_src[pos] = s;
}

// ---------------- MFMA GEMM + fused alpha epilogue, XCD-grouped grid ----------------
// Round-12 dbuf k-pipeline kept (neutral, not harmful).  NBN = N/128.
template<bool MAYBE_F32, int NBN>
__launch_bounds__(256)
__global__ void gemm_bf16(const void* __restrict__ Av, const bf16_t* __restrict__ BT,
                          bf16_t* __restrict__ C, int M, int N, int K,
                          const bf16_t* __restrict__ a_src, const bf16_t* __restrict__ a_dst,
                          float* __restrict__ as, float* __restrict__ ad, int H) {
  bool isbf = MAYBE_F32 ? detect_bf16((const unsigned short*)Av) : true;
  const bf16_t* A  = (const bf16_t*)Av;
  const float*  Af = (const float*)Av;
  __shared__ bf16_t As[2][128 * 32];
  __shared__ bf16_t Bs[2][128 * 32];
  __shared__ float sred[2][128];
  __shared__ float dred[2][128];
  const int tid  = threadIdx.x;
  const int lane = tid & 63;
  const int w    = tid >> 6;
  const int wm   = w & 1, wn = w >> 1;
  // XCD-grouped decode: id%8 == bm%8
  const int id   = blockIdx.x;
  const int bmq  = id / (8 * NBN);
  const int rem  = id % (8 * NBN);
  const int bm   = (bmq * 8 + (rem & 7)) * 128;
  const int bn   = (rem >> 3) * 128;
  const int quad = lane >> 4;
  const int l16  = lane & 15;
  const int hd   = bn >> 7;            // head owned by this block column

  f32x4 zero = {0.f, 0.f, 0.f, 0.f};
  f32x4 acc[4][4];
  for (int i = 0; i < 4; ++i)
    for (int j = 0; j < 4; ++j) acc[i][j] = zero;

  const int c0 = tid, c1 = tid + 256;         // 16B chunks of the 128x32 tile
  const int r0 = c0 >> 2, s0 = c0 & 3;
  const int r1 = c1 >> 2, s1 = c1 & 3;
  int ga0 = bm + r0; if (ga0 > M - 1) ga0 = M - 1;   // clamp: garbage rows never stored
  int ga1 = bm + r1; if (ga1 > M - 1) ga1 = M - 1;

  // issue the 4 async global->LDS loads for k-tile k0 into buffer b
  auto stage = [&](int b, int k0) {
    __builtin_amdgcn_global_load_lds(
        (const __attribute__((address_space(1))) void*)(A + (size_t)ga0 * K + k0 + s0 * 8),
        (__attribute__((address_space(3))) void*)(&As[b][(size_t)(w * 64) * 8]), 16, 0, 0);
    __builtin_amdgcn_global_load_lds(
        (const __attribute__((address_space(1))) void*)(BT + (size_t)(bn + r0) * K + k0 + s0 * 8),
        (__attribute__((address_space(3))) void*)(&Bs[b][(size_t)(w * 64) * 8]), 16, 0, 0);
    __builtin_amdgcn_global_load_lds(
        (const __attribute__((address_space(1))) void*)(A + (size_t)ga1 * K + k0 + s1 * 8),
        (__attribute__((address_space(3))) void*)(&As[b][(size_t)(256 + w * 64) * 8]), 16, 0, 0);
    __builtin_amdgcn_global_load_lds(
        (const __attribute__((address_space(1))) void*)(BT + (size_t)(bn + r1) * K + k0 + s1 * 8),
        (__attribute__((address_space(3))) void*)(&Bs[b][(size_t)(256 + w * 64) * 8]), 16, 0, 0);
  };

  auto mma_step = [&](int b) {
    bf16x8 af[4], bfr[4];
    for (int mt = 0; mt < 4; ++mt) {
      int m_local = wm * 64 + mt * 16 + l16;
      af[mt] = *(const bf16x8*)(&As[b][m_local * 32 + quad * 8]);
    }
    for (int nt = 0; nt < 4; ++nt) {
      int n_local = wn * 64 + nt * 16 + l16;
      bfr[nt] = *(const bf16x8*)(&Bs[b][n_local * 32 + quad * 8]);
    }
    for (int mt = 0; mt < 4; ++mt)
      for (int nt = 0; nt < 4; ++nt)
        acc[mt][nt] = __builtin_amdgcn_mfma_f32_16x16x32_bf16(af[mt], bfr[nt], acc[mt][nt], 0, 0, 0);
  };

  if (!MAYBE_F32 || isbf) {
    // ---- bf16 path: dbuf pipeline.  Tile t+1 loads fly across tile t's compute.
    stage(0, 0);
    __syncthreads();                    // tile 0 landed
    const int NT = K >> 5;
    for (int t = 0; t < NT; ++t) {
      int cur = t & 1;
      if (t + 1 < NT) stage(cur ^ 1, (t + 1) << 5);
      mma_step(cur);
      __syncthreads();                  // drains t+1 loads; all reads of buf[cur] done
    }
  } else {
    // ---- f32 input path (layer 1 when x is f32): original reg-staged single-buffer
    for (int k0 = 0; k0 < K; k0 += 32) {
      bf16x8 va0, va1;
      const float* p0 = Af + (size_t)ga0 * K + k0 + s0 * 8;
      const float* p1 = Af + (size_t)ga1 * K + k0 + s1 * 8;
      f32x4 l0 = *(const f32x4*)p0, h0 = *(const f32x4*)(p0 + 4);
      f32x4 l1 = *(const f32x4*)p1, h1 = *(const f32x4*)(p1 + 4);
      for (int j = 0; j < 4; ++j) {
        va0[j] = (bf16_t)l0[j]; va0[j + 4] = (bf16_t)h0[j];
        va1[j] = (bf16_t)l1[j]; va1[j + 4] = (bf16_t)h1[j];
      }
      bf16x8 vb0 = *(const bf16x8*)(BT + (size_t)(bn + r0) * K + k0 + s0 * 8);
      bf16x8 vb1 = *(const bf16x8*)(BT + (size_t)(bn + r1) * K + k0 + s1 * 8);
      __syncthreads();
      *(bf16x8*)(&As[0][c0 * 8]) = va0;
      *(bf16x8*)(&Bs[0][c0 * 8]) = vb0;
      *(bf16x8*)(&As[0][c1 * 8]) = va1;
      *(bf16x8*)(&Bs[0][c1 * 8]) = vb1;
      __syncthreads();
      mma_step(0);
    }
  }

  // ---- C store.  C/D layout: col=lane&15, row=(lane>>4)*4+r   [m89-verified]
  for (int mt = 0; mt < 4; ++mt) {
    for (int r = 0; r < 4; ++r) {
      int m = bm + wm * 64 + mt * 16 + quad * 4 + r;
      if (m >= M) continue;
      for (int nt = 0; nt < 4; ++nt) {
        int n = bn + wn * 64 + nt * 16 + l16;
        C[(size_t)m * N + n] = (bf16_t)acc[mt][nt][r];
      }
    }
  }

  // ---- fused alpha epilogue: per-row dots over this block's 128 columns
  float av[4], dv[4];
  for (int nt = 0; nt < 4; ++nt) {
    int ch = wn * 64 + nt * 16 + l16;            // channel within head
    av[nt] = (float)a_src[hd * 128 + ch];
    dv[nt] = (float)a_dst[hd * 128 + ch];
  }
  for (int mt = 0; mt < 4; ++mt) {
    for (int r = 0; r < 4; ++r) {
      float s = acc[mt][0][r] * av[0] + acc[mt][1][r] * av[1]
              + acc[mt][2][r] * av[2] + acc[mt][3][r] * av[3];
      float d = acc[mt][0][r] * dv[0] + acc[mt][1][r] * dv[1]
              + acc[mt][2][r] * dv[2] + acc[mt][3][r] * dv[3];
      for (int o = 1; o < 16; o <<= 1) {
        s += __shfl_xor(s, o);
        d += __shfl_xor(d, o);
      }
      if (l16 == 0) {
        int row_local = wm * 64 + mt * 16 + quad * 4 + r;
        sred[wn][row_local] = s;
        dred[wn][row_local] = d;
      }
    }
  }
  __syncthreads();
  if (tid < 128) {
    int m = bm + tid;
    if (m < M) {
      as[m * H + hd] = sred[0][tid] + sred[1][tid];
      ad[m * H + hd] = dred[0][tid] + dred[1][tid];
    }
  }
}

// ---------------- fused softmax + aggregation + bias + ELU ---------------------------
// Round-15: wide gathers kept (round-14 lesson: cost = gather-instruction count x
// latency / MLP, payload width nearly free -> never shrink payload).  MLP doubled via
// TWO independent 4-edge chains (separate accA/accB, denA/denB) + sched_barrier(0)
// pinning all 8 loads before the compute phase (round-11's unroll-8 failed because
// the compiler sank loads into the single dependence chain; VGPR stayed 36).
// __launch_bounds__(256,4) grants the ~80-VGPR budget: 16 waves/CU x 8 in flight = 128
// vs 20 x 4 = 80 before.
template<int CPL>
__launch_bounds__(256, 4)
__global__ void agg_fused(const bf16_t* __restrict__ h, const int* __restrict__ off,
                          const int* __restrict__ csr_src, const float* __restrict__ as,
                          const float* __restrict__ ad, const bf16_t* __restrict__ bias,
                          bf16_t* __restrict__ outp, int H) {
  typedef __bf16 vec_t __attribute__((ext_vector_type(CPL)));
  const int C = CPL * 64;
  int lane = threadIdx.x & 63;
  int n = blockIdx.x * 4 + (threadIdx.x >> 6);
  if (n >= N_NODES) return;
  int start = __builtin_amdgcn_readfirstlane(off[n]);
  int end   = __builtin_amdgcn_readfirstlane(off[n + 1]);
  int c0 = lane * CPL;
  int hd = c0 >> 7;
  float adv = ad[n * H + hd];
  float accA[CPL], accB[CPL];
  for (int j = 0; j < CPL; ++j) { accA[j] = 0.f; accB[j] = 0.f; }
  float denA = 0.f, denB = 0.f;

  int pos = start;
  for (; pos + 7 < end; pos += 8) {
    int s0 = __builtin_amdgcn_readfirstlane(csr_src[pos]);
    int s1 = __builtin_amdgcn_readfirstlane(csr_src[pos + 1]);
    int s2 = __builtin_amdgcn_readfirstlane(csr_src[pos + 2]);
    int s3 = __builtin_amdgcn_readfirstlane(csr_src[pos + 3]);
    int s4 = __builtin_amdgcn_readfirstlane(csr_src[pos + 4]);
    int s5 = __builtin_amdgcn_readfirstlane(csr_src[pos + 5]);
    int s6 = __builtin_amdgcn_readfirstlane(csr_src[pos + 6]);
    int s7 = __builtin_amdgcn_readfirstlane(csr_src[pos + 7]);
    // issue all 8 row gathers + 8 alpha gathers, THEN compute (sched_barrier pins it)
    vec_t hv0 = *(const vec_t*)(h + (size_t)s0 * C + c0);
    vec_t hv1 = *(const vec_t*)(h + (size_t)s1 * C + c0);
    vec_t hv2 = *(const vec_t*)(h + (size_t)s2 * C + c0);
    vec_t hv3 = *(const vec_t*)(h + (size_t)s3 * C + c0);
    vec_t hv4 = *(const vec_t*)(h + (size_t)s4 * C + c0);
    vec_t hv5 = *(const vec_t*)(h + (size_t)s5 * C + c0);
    vec_t hv6 = *(const vec_t*)(h + (size_t)s6 * C + c0);
    vec_t hv7 = *(const vec_t*)(h + (size_t)s7 * C + c0);
    float e0 = as[s0 * H + hd];
    float e1 = as[s1 * H + hd];
    float e2 = as[s2 * H + hd];
    float e3 = as[s3 * H + hd];
    float e4 = as[s4 * H + hd];
    float e5 = as[s5 * H + hd];
    float e6 = as[s6 * H + hd];
    float e7 = as[s7 * H + hd];
    __builtin_amdgcn_sched_barrier(0);   // loads above may not sink below this point
    e0 += adv; e0 = e0 > 0.f ? e0 : 0.2f * e0;
    e1 += adv; e1 = e1 > 0.f ? e1 : 0.2f * e1;
    e2 += adv; e2 = e2 > 0.f ? e2 : 0.2f * e2;
    e3 += adv; e3 = e3 > 0.f ? e3 : 0.2f * e3;
    e4 += adv; e4 = e4 > 0.f ? e4 : 0.2f * e4;
    e5 += adv; e5 = e5 > 0.f ? e5 : 0.2f * e5;
    e6 += adv; e6 = e6 > 0.f ? e6 : 0.2f * e6;
    e7 += adv; e7 = e7 > 0.f ? e7 : 0.2f * e7;
    float w0 = __expf(e0), w1 = __expf(e1), w2 = __expf(e2), w3 = __expf(e3);
    float w4 = __expf(e4), w5 = __expf(e5), w6 = __expf(e6), w7 = __expf(e7);
    denA += (w0 + w1) + (w2 + w3);
    denB += (w4 + w5) + (w6 + w7);
    for (int j = 0; j < CPL; ++j) {
      accA[j] += (w0 * (float)hv0[j] + w1 * (float)hv1[j])
               + (w2 * (float)hv2[j] + w3 * (float)hv3[j]);
      accB[j] += (w4 * (float)hv4[j] + w5 * (float)hv5[j])
               + (w6 * (float)hv6[j] + w7 * (float)hv7[j]);
    }
  }
  for (; pos + 3 < end; pos += 4) {
    int s0 = __builtin_amdgcn_readfirstlane(csr_src[pos]);
    int s1 = __builtin_amdgcn_readfirstlane(csr_src[pos + 1]);
    int s2 = __builtin_amdgcn_readfirstlane(csr_src[pos + 2]);
    int s3 = __builtin_amdgcn_readfirstlane(csr_src[pos + 3]);
    vec_t hv0 = *(const vec_t*)(h + (size_t)s0 * C + c0);
    vec_t hv1 = *(const vec_t*)(h + (size_t)s1 * C + c0);
    vec_t hv2 = *(const vec_t*)(h + (size_t)s2 * C + c0);
    vec_t hv3 = *(const vec_t*)(h + (size_t)s3 * C + c0);
    float e0 = as[s0 * H + hd] + adv; e0 = e0 > 0.f ? e0 : 0.2f * e0;
    float e1 = as[s1 * H + hd] + adv; e1 = e1 > 0.f ? e1 : 0.2f * e1;
    float e2 = as[s2 * H + hd] + adv; e2 = e2 > 0.f ? e2 : 0.2f * e2;
    float e3 = as[s3 * H + hd] + adv; e3 = e3 > 0.f ? e3 : 0.2f * e3;
    float w0 = __expf(e0), w1 = __expf(e1), w2 = __expf(e2), w3 = __expf(e3);
    denA += (w0 + w1) + (w2 + w3);
    for (int j = 0; j < CPL; ++j)
      accA[j] += (w0 * (float)hv0[j] + w1 * (float)hv1[j])
               + (w2 * (float)hv2[j] + w3 * (float)hv3[j]);
  }
  for (; pos < end; ++pos) {
    int s0 = __builtin_amdgcn_readfirstlane(csr_src[pos]);
    vec_t hv0 = *(const vec_t*)(h + (size_t)s0 * C + c0);
    float e0 = as[s0 * H + hd] + adv; e0 = e0 > 0.f ? e0 : 0.2f * e0;
    float w0 = __expf(e0);
    denA += w0;
    for (int j = 0; j < CPL; ++j) accA[j] += w0 * (float)hv0[j];
  }

  float inv = 1.f / ((denA + denB) + 1e-16f);
  vec_t ov;
  for (int j = 0; j < CPL; ++j) {
    float o = (accA[j] + accB[j]) * inv + (float)bias[c0 + j];
    o = o > 0.f ? o : expm1f(o);         // elu
    ov[j] = (bf16_t)o;
  }
  *(vec_t*)(outp + (size_t)n * C + c0) = ov;
}

// ---------------- merged mean-pool + FC: one block per graph, no atomics -------------
__launch_bounds__(256)
__global__ void pool_fc2(const bf16_t* __restrict__ h3, const int* __restrict__ batch,
                         const bf16_t* __restrict__ fcw, const bf16_t* __restrict__ fcb,
                         void* __restrict__ outp, const unsigned short* __restrict__ xu16) {
  bool isbf = detect_bf16(xu16);
  int g = blockIdx.x;
  int lo = 0, hi = N_NODES;
  while (lo < hi) { int mid = (lo + hi) >> 1; if (batch[mid] < g) lo = mid + 1; else hi = mid; }
  int start = lo;
  hi = N_NODES;
  while (lo < hi) { int mid = (lo + hi) >> 1; if (batch[mid] < g + 1) lo = mid + 1; else hi = mid; }
  int end = lo, cnt = end - start;

  int t = threadIdx.x;
  int wave = t >> 6, lane = t & 63;
  int c0 = lane * 2;
  float a0 = 0.f, a1 = 0.f;
  for (int n = start + wave; n < end; n += 4) {
    bf16x2 v = *(const bf16x2*)(h3 + (size_t)n * HID + c0);
    a0 += (float)v[0];
    a1 += (float)v[1];
  }
  __shared__ float red[4][HID];
  red[wave][c0] = a0;
  red[wave][c0 + 1] = a1;
  __syncthreads();
  __shared__ float pooled[HID];
  if (t < HID) {
    float s = red[0][t] + red[1][t] + red[2][t] + red[3][t];
    pooled[t] = s / (float)(cnt > 0 ? cnt : 1);
  }
  __syncthreads();
  if (t < OUT_CH) {
    float a = (float)fcb[t];
    for (int c = 0; c < HID; ++c) a += pooled[c] * (float)fcw[c * OUT_CH + t];
    if (isbf) ((bf16_t*)outp)[g * OUT_CH + t] = (bf16_t)a;
    else      ((float*)outp)[g * OUT_CH + t] = a;
  }
}

// ---------------- launcher ----------------
extern "C" void kernel_launch(void* const* d_in, const int* in_sizes, int n_in,
                              void* d_out, int out_size, void* d_ws, size_t ws_size,
                              hipStream_t stream) {
  const void* x    = d_in[0];
  const void* eidx = d_in[1];
  const void* batch= d_in[2];
  const void* W1   = d_in[3];
  const void* a_s1 = d_in[4];
  const void* a_d1 = d_in[5];
  const void* b1   = d_in[6];
  const void* W2   = d_in[7];
  const void* a_s2 = d_in[8];
  const void* a_d2 = d_in[9];
  const void* b2   = d_in[10];
  const void* W3   = d_in[11];
  const void* a_s3 = d_in[12];
  const void* a_d3 = d_in[13];
  const void* b3   = d_in[14];
  const void* fcw  = d_in[15];
  const void* fcb  = d_in[16];
  const unsigned short* xu16 = (const unsigned short*)x;

  char* p = (char*)d_ws;
  auto carve = [&](size_t nbytes) { char* r = p; p += (nbytes + 255) & ~(size_t)255; return r; };
  bf16_t*   W1T    = (bf16_t*)carve((size_t)512 * 256 * 2);
  bf16_t*   W2T    = (bf16_t*)carve((size_t)512 * 512 * 2);
  bf16_t*   W3T    = (bf16_t*)carve((size_t)128 * 512 * 2);
  bf16_t*   hA     = (bf16_t*)carve((size_t)M_PAD * 512 * 2);
  bf16_t*   hB     = (bf16_t*)carve((size_t)M_PAD * 512 * 2);
  bf16_t*   sm     = (bf16_t*)carve((size_t)32768 * 2);
  bf16_t *as1b = sm, *ad1b = sm + 512, *b1b = sm + 1024,
         *as2b = sm + 1536, *ad2b = sm + 2048, *b2b = sm + 2560,
         *as3b = sm + 3072, *ad3b = sm + 3200, *b3b = sm + 3328,
         *fcwb = sm + 3456, *fcbb = sm + 29056;
  float*    asb    = (float*)carve((size_t)N_NODES * 4 * 4);
  float*    adb    = (float*)carve((size_t)N_NODES * 4 * 4);
  int*      deg    = (int*)carve((size_t)N_NODES * 4);
  int*      off    = (int*)carve((size_t)(N_NODES + 1) * 4);
  int*      cursor = (int*)carve((size_t)N_NODES * 4);
  int*      csr_src= (int*)carve((size_t)E_TOT * 4);
  int*      esrc32 = (int*)carve((size_t)N_EDGES * 4);
  int*      edst32 = (int*)carve((size_t)N_EDGES * 4);
  int*      bat32  = (int*)carve((size_t)N_NODES * 4);

  dim3 b256(256);
  const int NG4 = (N_NODES + 3) / 4;   // wave-per-node grids

  SmallCvt tab;
  const void* srcs[11] = {a_s1, a_d1, b1, a_s2, a_d2, b2, a_s3, a_d3, b3, fcw, fcb};
  bf16_t* dsts[11] = {as1b, ad1b, b1b, as2b, ad2b, b2b, as3b, ad3b, b3b, fcwb, fcbb};
  int ns[11] = {512, 512, 512, 512, 512, 512, 128, 128, 128, 25600, 200};
  for (int i = 0; i < 11; ++i) { tab.src[i] = srcs[i]; tab.dst[i] = dsts[i]; tab.n[i] = ns[i]; }

  hipMemsetAsync(deg, 0, (size_t)N_NODES * 4, stream);
  prep<<<dim3((458752 + 29256 + 255) / 256), b256, 0, stream>>>(
      W1, W2, W3, W1T, W2T, W3T, tab, xu16,
      (const int*)eidx, (const int*)batch, esrc32, edst32, bat32, deg);

  // CSR-by-dst (src-only payload; reused by all 3 layers)
  scan_deg_block<<<dim3(1), dim3(1024), 0, stream>>>(deg, off, cursor);
  scatter_kernel<<<dim3((E_TOT + 255) / 256), b256, 0, stream>>>(esrc32, edst32, off, cursor, csr_src);

  // XCD-grouped 1-D gemm grids: 160 bm slots (157 used) x NBN bn
  const int G4 = 160 * 4, G1 = 160 * 1;

  // ---- layer 1: x (raw, dtype-detected in-kernel) -> hA[.,512] + alpha -> agg -> hB
  gemm_bf16<true, 4><<<dim3(G4), b256, 0, stream>>>(x, W1T, hA, N_NODES, 512, 256,
                                                    as1b, ad1b, asb, adb, 4);
  agg_fused<8><<<dim3(NG4), b256, 0, stream>>>(hA, off, csr_src, asb, adb, b1b, hB, 4);

  // ---- layer 2
  gemm_bf16<false, 4><<<dim3(G4), b256, 0, stream>>>(hB, W2T, hA, N_NODES, 512, 512,
                                                     as2b, ad2b, asb, adb, 4);
  agg_fused<8><<<dim3(NG4), b256, 0, stream>>>(hA, off, csr_src, asb, adb, b2b, hB, 4);

  // ---- layer 3
  gemm_bf16<false, 1><<<dim3(G1), b256, 0, stream>>>(hB, W3T, hA, N_NODES, 128, 512,
                                                     as3b, ad3b, asb, adb, 1);
  agg_fused<2><<<dim3(NG4), b256, 0, stream>>>(hA, off, csr_src, asb, adb, b3b, hB, 1);

  // ---- merged mean-pool + FC
  pool_fc2<<<dim3(NUM_GRAPHS), b256, 0, stream>>>(hB, bat32, fcwb, fcbb, d_out, xu16);
}